// Round 5
// baseline (1928.967 us; speedup 1.0000x reference)
//
#include <hip/hip_runtime.h>

#define BB 32      // 32 blocks x 2 batch elements each = 64
#define TT 2048
#define II 64
#define HH 256
#define NTHR 512   // 8 waves: waves 0-3 = batch group 0, waves 4-7 = group 1

typedef __fp16 h2_t __attribute__((ext_vector_type(2)));
typedef __fp16 h8_t __attribute__((ext_vector_type(8)));

#define H2(i) __builtin_bit_cast(h2_t, (i))
#define I32(h) __builtin_bit_cast(int, (h))

#if __has_builtin(__builtin_amdgcn_fdot2)
#define FDOT2(a, b, c) __builtin_amdgcn_fdot2((a), (b), (c), false)
#else
__device__ __forceinline__ float FDOT2(h2_t a, h2_t b, float c) {
    return fmaf((float)a[0], (float)b[0], fmaf((float)a[1], (float)b[1], c));
}
#endif

// tanh(x) = 1 - 2/(e^{2x}+1); v_exp + v_rcp, correct limits at +-inf.
__device__ __forceinline__ float ftanh(float x) {
    float e = __expf(2.0f * x);
    return 1.0f - 2.0f * __builtin_amdgcn_rcpf(e + 1.0f);
}

// DPP ctrl: 0xB1 quad_perm ^1, 0x4E quad_perm ^2, 0x124 row_ror:4,
// 0x12C row_ror:12, 0x140 ROW_MIRROR, 0x141 ROW_HALF_MIRROR, 0x142 BCAST15.
// Direction (R3 lesson): row_ror:N = dst[i] <- src[(i-N) mod 16].
template <int CTRL>
__device__ __forceinline__ float dpp_add(float v) {
    int s = __builtin_amdgcn_update_dpp(0, __float_as_int(v), CTRL, 0xF, 0xF, true);
    return v + __int_as_float(s);
}
template <int CTRL>
__device__ __forceinline__ float dpp_get(float v) {
    int s = __builtin_amdgcn_update_dpp(0, __float_as_int(v), CTRL, 0xF, 0xF, true);
    return __int_as_float(s);
}

// merge-reduce, ALL-DPP (harness-verified in R4). lane^4 per 16-lane row:
//   bit2==0 lanes need src[i+4] -> row_ror:12 ; bit2==1 need src[i-4] -> ror:4
__device__ __forceinline__ float mrg4(float a, float b, int lane) {
    float t = (lane & 4) ? b : a;
    float u = (lane & 4) ? a : b;
    float r4  = dpp_get<0x124>(u);
    float r12 = dpp_get<0x12C>(u);
    return t + ((lane & 4) ? r4 : r12);
}
__device__ __forceinline__ float mrg2(float a, float b, int lane) {
    float t = (lane & 2) ? b : a;
    float u = (lane & 2) ? a : b;
    return t + dpp_get<0x4E>(u);
}
__device__ __forceinline__ float mrg1(float a, float b, int lane) {
    float t = (lane & 1) ? b : a;
    float u = (lane & 1) ? a : b;
    return t + dpp_get<0xB1>(u);
}

// R5: TWO independent recurrences per block (2 batch elements), 2 waves/SIMD.
// R4 evidence: step ~1300cy with only ~500cy of per-wave issue -> the SIMD
// idles in dependency stalls with 1 wave resident. The co-resident wave here
// is an INDEPENDENT batch element (per-wave work identical to R4, unlike R2
// which split one recurrence 8 ways and doubled same-h LDS traffic). One
// block-wide s_barrier per step orders both groups' h-publish; HW wave
// interleaving provides the stall-fill.
__launch_bounds__(NTHR, 2)
__global__ void rnn_fused(const float* __restrict__ x,
                          const float* __restrict__ W_ih,
                          const float* __restrict__ W_hh,
                          const float* __restrict__ b_ih,
                          const float* __restrict__ b_hh,
                          const float* __restrict__ W_fc,
                          const float* __restrict__ b_fc,
                          float* __restrict__ out) {
    // hbuf[g][p][c][j] = group g's h[c*64+j], fp16, double-buffered.
    // Group stride 1024 B (bank-aligned), buffer stride 512 B. Read addr =
    // g*1024 + p*512 + c*128 + q*16 -> bank 4q, conflict-free broadcast;
    // write addr = ... + wg*128 + lane*2 -> 2 lanes/word, free.
    __shared__ __align__(16) __fp16 hbuf[2][2][4][64];
    // part[g][i+1][..] = head partials of group g, step i (deferred 1 step)
    __shared__ float part[2][TT + 1][8];

    const int tid  = threadIdx.x;
    const int lane = tid & 63;
    const int wv   = tid >> 6;       // wave 0..7
    const int g    = wv >> 2;        // batch group 0/1
    const int wg   = wv & 3;         // wave within group 0..3
    const int b    = blockIdx.x * 2 + g;
    const int o    = lane >> 3;      // row sub-slot 0..7
    const int q    = lane & 7;       // k-slice 0..7

    // thread owns rows wg*64 + o*8 + r (r=0..7); cols: chunk c -> 
    // [c*64 + q*8, c*64 + q*8 + 8). Weights identical for both groups.
    int whh_i[8][16];  // 128 VGPRs (fp16 pairs as int), j = c*4 + e
    int wih_i[8][4];   //  32 VGPRs
#pragma unroll
    for (int r = 0; r < 8; ++r) {
        const int t_r = wg * 64 + o * 8 + r;
#pragma unroll
        for (int c = 0; c < 4; ++c) {
            const float4* wr = (const float4*)(W_hh + t_r * HH + c * 64 + q * 8);
            const float4 wa = wr[0], wb = wr[1];
            whh_i[r][c * 4 + 0] = I32(__builtin_amdgcn_cvt_pkrtz(wa.x, wa.y));
            whh_i[r][c * 4 + 1] = I32(__builtin_amdgcn_cvt_pkrtz(wa.z, wa.w));
            whh_i[r][c * 4 + 2] = I32(__builtin_amdgcn_cvt_pkrtz(wb.x, wb.y));
            whh_i[r][c * 4 + 3] = I32(__builtin_amdgcn_cvt_pkrtz(wb.z, wb.w));
        }
        const float4* wi = (const float4*)(W_ih + t_r * II + q * 8);
        const float4 wa = wi[0], wb = wi[1];
        wih_i[r][0] = I32(__builtin_amdgcn_cvt_pkrtz(wa.x, wa.y));
        wih_i[r][1] = I32(__builtin_amdgcn_cvt_pkrtz(wa.z, wa.w));
        wih_i[r][2] = I32(__builtin_amdgcn_cvt_pkrtz(wb.x, wb.y));
        wih_i[r][3] = I32(__builtin_amdgcn_cvt_pkrtz(wb.z, wb.w));
    }
    // pin weights into VGPRs: asm def cannot be rematerialized from memory
#pragma unroll
    for (int j = 0; j < 128; ++j) asm volatile("" : "+v"(((int*)whh_i)[j]));
#pragma unroll
    for (int j = 0; j < 32; ++j) asm volatile("" : "+v"(((int*)wih_i)[j]));

    // merge tree ends with lane owning row wg*64+lane (harness-verified R1/R4)
    const int myrow = wg * 64 + lane;
    const float bias = b_ih[myrow] + b_hh[myrow];
    const float wfc  = W_fc[myrow];
    const float bfc  = b_fc[0];

    for (int idx = tid; idx < 2 * 2 * 256; idx += NTHR)
        ((__fp16*)hbuf)[idx] = (__fp16)0.0f;
    __syncthreads();

    const float* xbase = x + (size_t)b * TT * II + q * 8;
    float* outb = out + (size_t)b * TT;
    float (*partg)[8] = part[g];

    // write: own row -> chunk wg, slot lane.  read: chunk c at q*16 bytes.
    char* hbg = (char*)&hbuf[g][0][0][0];
    __fp16* hw0 = (__fp16*)(hbg + 0 * 512 + wg * 128 + lane * 2);
    __fp16* hw1 = (__fp16*)(hbg + 1 * 512 + wg * 128 + lane * 2);
    const char* hq0 = hbg + 0 * 512 + q * 16;
    const char* hq1 = hbg + 1 * 512 + q * 16;

    // x pipeline: xc = converted row i; slots A/B hold raw rows i+1, i+2
    h2_t xc[4];
    float4 sAa, sAc, sBa, sBc;
    {
        const float4* xp = (const float4*)(xbase);
        const float4 a = xp[0], c = xp[1];
        xc[0] = __builtin_amdgcn_cvt_pkrtz(a.x, a.y);
        xc[1] = __builtin_amdgcn_cvt_pkrtz(a.z, a.w);
        xc[2] = __builtin_amdgcn_cvt_pkrtz(c.x, c.y);
        xc[3] = __builtin_amdgcn_cvt_pkrtz(c.z, c.w);
        const float4* x1 = (const float4*)(xbase + II);
        sAa = x1[0]; sAc = x1[1];
        const float4* x2 = (const float4*)(xbase + 2 * II);
        sBa = x2[0]; sBc = x2[1];
    }

    float hn_prev = 0.0f;  // step-(-1) head -> part[g][0] (never read)

    // One step. HRD: read base (this step's h buffer, at q*16). HWOUT: write
    // ptr for h_{i+1}. SA/SC: raw x row IDX+1 (consumed; refilled IDX+3).
#define STEP(IDX, HRD, HWOUT, SA, SC)                                          \
    {                                                                          \
        /* issue all 4 chunk reads first; latency hidden by head + x-dots */   \
        const h8_t hv0 = *(const h8_t*)((HRD) + 0 * 128);                      \
        const h8_t hv1 = *(const h8_t*)((HRD) + 1 * 128);                      \
        const h8_t hv2 = *(const h8_t*)((HRD) + 2 * 128);                      \
        const h8_t hv3 = *(const h8_t*)((HRD) + 3 * 128);                      \
        /* ---- deferred head of step IDX-1: pure-DPP 32-lane reduce ---- */   \
        {                                                                      \
            float hc = hn_prev * wfc;                                          \
            hc = dpp_add<0xB1>(hc);   /* ^1 */                                 \
            hc = dpp_add<0x4E>(hc);   /* ^2 */                                 \
            hc = dpp_add<0x141>(hc);  /* HALF_MIRROR: eff ^4 */                \
            hc = dpp_add<0x140>(hc);  /* ROW_MIRROR: eff ^8 */                 \
            hc = dpp_add<0x142>(hc);  /* BCAST15: lanes 16/48 hold sums */     \
            if ((lane & 31) == 16) partg[IDX][wg * 2 + (lane >> 5)] = hc;      \
        }                                                                      \
        /* ---- x-dots first: h-independent, fills h-read latency ---- */      \
        float a0, a1, a2, a3, a4, a5, a6, a7;                                  \
        a0 = FDOT2(H2(wih_i[0][0]), xc[0], 0.0f);                              \
        a1 = FDOT2(H2(wih_i[1][0]), xc[0], 0.0f);                              \
        a2 = FDOT2(H2(wih_i[2][0]), xc[0], 0.0f);                              \
        a3 = FDOT2(H2(wih_i[3][0]), xc[0], 0.0f);                              \
        a4 = FDOT2(H2(wih_i[4][0]), xc[0], 0.0f);                              \
        a5 = FDOT2(H2(wih_i[5][0]), xc[0], 0.0f);                              \
        a6 = FDOT2(H2(wih_i[6][0]), xc[0], 0.0f);                              \
        a7 = FDOT2(H2(wih_i[7][0]), xc[0], 0.0f);                              \
        _Pragma("unroll")                                                      \
        for (int e = 1; e < 4; ++e) {                                          \
            a0 = FDOT2(H2(wih_i[0][e]), xc[e], a0);                            \
            a1 = FDOT2(H2(wih_i[1][e]), xc[e], a1);                            \
            a2 = FDOT2(H2(wih_i[2][e]), xc[e], a2);                            \
            a3 = FDOT2(H2(wih_i[3][e]), xc[e], a3);                            \
            a4 = FDOT2(H2(wih_i[4][e]), xc[e], a4);                            \
            a5 = FDOT2(H2(wih_i[5][e]), xc[e], a5);                            \
            a6 = FDOT2(H2(wih_i[6][e]), xc[e], a6);                            \
            a7 = FDOT2(H2(wih_i[7][e]), xc[e], a7);                            \
        }                                                                      \
        /* consume x slot (row IDX+1), refill with row IDX+3 */                \
        xc[0] = __builtin_amdgcn_cvt_pkrtz((SA).x, (SA).y);                    \
        xc[1] = __builtin_amdgcn_cvt_pkrtz((SA).z, (SA).w);                    \
        xc[2] = __builtin_amdgcn_cvt_pkrtz((SC).x, (SC).y);                    \
        xc[3] = __builtin_amdgcn_cvt_pkrtz((SC).z, (SC).w);                    \
        {                                                                      \
            const int rn = ((IDX) + 3 < TT) ? ((IDX) + 3) : (TT - 1);          \
            const float4* xp = (const float4*)(xbase + rn * II);               \
            (SA) = xp[0]; (SC) = xp[1];                                        \
        }                                                                      \
        /* ---- h-dots: chunk-wise, lgkm-pipelined by the compiler ---- */     \
        _Pragma("unroll")                                                      \
        for (int c = 0; c < 4; ++c) {                                          \
            const h8_t hv = (c == 0) ? hv0 : (c == 1) ? hv1                    \
                          : (c == 2) ? hv2 : hv3;                              \
            _Pragma("unroll")                                                  \
            for (int e = 0; e < 4; ++e) {                                      \
                const h2_t he = (e == 0) ? __builtin_shufflevector(hv, hv, 0, 1) \
                              : (e == 1) ? __builtin_shufflevector(hv, hv, 2, 3) \
                              : (e == 2) ? __builtin_shufflevector(hv, hv, 4, 5) \
                                         : __builtin_shufflevector(hv, hv, 6, 7); \
                const int j = c * 4 + e;                                       \
                a0 = FDOT2(H2(whh_i[0][j]), he, a0);                           \
                a1 = FDOT2(H2(whh_i[1][j]), he, a1);                           \
                a2 = FDOT2(H2(whh_i[2][j]), he, a2);                           \
                a3 = FDOT2(H2(whh_i[3][j]), he, a3);                           \
                a4 = FDOT2(H2(whh_i[4][j]), he, a4);                           \
                a5 = FDOT2(H2(whh_i[5][j]), he, a5);                           \
                a6 = FDOT2(H2(whh_i[6][j]), he, a6);                           \
                a7 = FDOT2(H2(whh_i[7][j]), he, a7);                           \
            }                                                                  \
        }                                                                      \
        /* ---- merge-reduce (pure DPP, no LDS ops) ---- */                    \
        const float A0 = mrg4(a0, a4, lane);                                   \
        const float A1 = mrg4(a1, a5, lane);                                   \
        const float A2 = mrg4(a2, a6, lane);                                   \
        const float A3 = mrg4(a3, a7, lane);                                   \
        const float B0 = mrg2(A0, A2, lane);                                   \
        const float B1 = mrg2(A1, A3, lane);                                   \
        const float C0 = mrg1(B0, B1, lane);                                   \
        const float hn = ftanh(C0 + bias);                                     \
        (HWOUT)[0] = (__fp16)hn;                                               \
        hn_prev = hn;                                                          \
        /* LDS-only barrier: h_{IDX+1} visible for BOTH groups; vmcnt NOT */   \
        /* drained (x prefetch stays in flight across steps) */                \
        asm volatile("s_waitcnt lgkmcnt(0)\n\ts_barrier" ::: "memory");        \
    }

    for (int ib = 0; ib < TT; ib += 2) {
        STEP(ib, hq0, hw1, sAa, sAc)
        STEP(ib + 1, hq1, hw0, sBa, sBc)
    }
#undef STEP

    // final head (step TT-1) -> part[g][TT]
    {
        float hc = hn_prev * wfc;
        hc = dpp_add<0xB1>(hc);
        hc = dpp_add<0x4E>(hc);
        hc = dpp_add<0x141>(hc);
        hc = dpp_add<0x140>(hc);
        hc = dpp_add<0x142>(hc);
        if ((lane & 31) == 16) partg[TT][wg * 2 + (lane >> 5)] = hc;
    }
    __syncthreads();

    // ---- deferred output head: out[b][i] = sum(part[g][i+1][:]) + bfc ----
    // 256 threads per group handle that group's batch element.
    const int tg = tid & 255;
    for (int i = tg; i < TT; i += 256) {
        const float4* pp = (const float4*)&partg[i + 1][0];
        const float4 s0 = pp[0], s1 = pp[1];
        outb[i] = s0.x + s0.y + s0.z + s0.w + s1.x + s1.y + s1.z + s1.w + bfc;
    }
}

extern "C" void kernel_launch(void* const* d_in, const int* in_sizes, int n_in,
                              void* d_out, int out_size, void* d_ws, size_t ws_size,
                              hipStream_t stream) {
    const float* x    = (const float*)d_in[0];
    const float* W_ih = (const float*)d_in[1];
    const float* W_hh = (const float*)d_in[2];
    const float* b_ih = (const float*)d_in[3];
    const float* b_hh = (const float*)d_in[4];
    const float* W_fc = (const float*)d_in[5];
    const float* b_fc = (const float*)d_in[6];
    float* out = (float*)d_out;

    rnn_fused<<<BB, NTHR, 0, stream>>>(x, W_ih, W_hh, b_ih, b_hh, W_fc, b_fc, out);
}

// Round 6
// 1426.818 us; speedup vs baseline: 1.3519x; 1.3519x over previous
//
#include <hip/hip_runtime.h>

#define BB 64
#define TT 2048
#define II 64
#define HH 256
#define NTHR 256

typedef _Float16 v8h __attribute__((ext_vector_type(8)));
typedef float v4f __attribute__((ext_vector_type(4)));
typedef int v4i __attribute__((ext_vector_type(4)));
typedef int v2i __attribute__((ext_vector_type(2)));
typedef unsigned long long u64;

#define PK(a, b) __builtin_bit_cast(int, __builtin_amdgcn_cvt_pkrtz((a), (b)))
#define MFMA __builtin_amdgcn_mfma_f32_16x16x32_f16
// B fragment (tc,T) from pinned ints -> v8h (static indices only, rule #20)
#define BF(tc, T) __builtin_bit_cast(v8h, (v4i){bi[tc][T][0], bi[tc][T][1], bi[tc][T][2], bi[tc][T][3]})

// tanh(x) = 1 - 2/(e^{2x}+1); v_exp + v_rcp, correct limits at +-inf.
__device__ __forceinline__ float ftanh(float x) {
    float e = __expf(2.0f * x);
    return 1.0f - 2.0f * __builtin_amdgcn_rcpf(e + 1.0f);
}

// DPP ctrl: 0xB1 quad ^1, 0x4E quad ^2, 0x141 ROW_HALF_MIRROR (^7 -> eff ^4
// after ^1,^2), 0x140 ROW_MIRROR (^15 -> eff ^8). 16-lane-row scoped.
template <int CTRL>
__device__ __forceinline__ float dpp_add(float v) {
    int s = __builtin_amdgcn_update_dpp(0, __float_as_int(v), CTRL, 0xF, 0xF, true);
    return v + __int_as_float(s);
}

// hardware transpose read: 16-lane group reads 128B at addr[l]=base+(l&15)*8,
// lane l elem j = region_half[(l&15) + 16*j]  (m156/m162 semantics)
template <int OFF>
__device__ __forceinline__ u64 trread(unsigned a) {
    u64 d;
    asm volatile("ds_read_b64_tr_b16 %0, %1 offset:%2" : "=v"(d) : "v"(a), "i"(OFF));
    return d;
}
// rule #18: inline-asm lgkmcnt needs a following sched_barrier(0), else the
// compiler hoists register-only MFMA past the wait.
template <int N>
__device__ __forceinline__ void lgkm_wait() {
    asm volatile("s_waitcnt lgkmcnt(%0)" : : "i"(N) : "memory");
    __builtin_amdgcn_sched_barrier(0);
}
__device__ __forceinline__ v8h frag2(u64 lo, u64 hi) {
    v2i a = __builtin_bit_cast(v2i, lo);
    v2i b = __builtin_bit_cast(v2i, hi);
    v4i r = {a.x, a.y, b.x, b.y};
    return __builtin_bit_cast(v8h, r);
}
__device__ __forceinline__ v8h xfrag(const float4 s0, const float4 s1) {
    v4i r = {PK(s0.x, s0.y), PK(s0.z, s0.w), PK(s1.x, s1.y), PK(s1.z, s1.w)};
    return __builtin_bit_cast(v8h, r);
}

// R6: dots moved VALU -> MFMA pipe. R5 evidence: active CUs are ISSUE-bound
// (83% VALU-busy at 32 CUs); fdot2 ~4cy/wave => R4's 160 fdot2 = ~640cy issue
// floor. Here: 40 mfma_16x16x32_f16 per wave (~200cy matrix pipe), VALU keeps
// only tanh/head/pack (~200cy). One batch element per block, M=16 with rows
// 1-15 identically zero (LDS h-slots b>=1 zeroed once, never written).
// h in LDS k-major [256][16] fp16, double-buffered; A-frags via
// ds_read_b64_tr_b16 pairs; B-frags (W^T) pinned in VGPRs with the SAME
// (g,j)->k map as A => result invariant to the hw's internal k-slot order.
// C/D: col=lane&15, row=4*(lane>>4)+reg (m89-verified); row 0 = the batch.
// Head: 4-DPP 16-lane reduce + 1 fp32 atomicAdd per wave per step (out is
// memset-0 by the harness; the old part[] LDS buffer is gone).
__launch_bounds__(NTHR, 1)
__global__ void rnn_fused(const float* __restrict__ x,
                          const float* __restrict__ W_ih,
                          const float* __restrict__ W_hh,
                          const float* __restrict__ b_ih,
                          const float* __restrict__ b_hh,
                          const float* __restrict__ W_fc,
                          const float* __restrict__ b_fc,
                          float* __restrict__ out) {
    __shared__ __align__(16) __fp16 hlds[2][HH][16];  // 16 KB total

    const int tid  = threadIdx.x;
    const int b    = blockIdx.x;
    const int lane = tid & 63;
    const int w    = tid >> 6;     // wave 0..3: output cols [64w, 64w+64)
    const int g    = lane >> 4;    // 16-lane group 0..3
    const int c16  = lane & 15;

    // ---- B fragments: bi[tc][T][4]: lane (g,c16) slot j holds
    // W[n = 64w+16tc+c16][k = 32T + 8g + j]  (T=8,9 -> W_ih, k-256)
    int bi[4][10][4];  // 160 VGPRs
    float bv[4], wf[4];
#pragma unroll
    for (int tc = 0; tc < 4; ++tc) {
        const int n = 64 * w + 16 * tc + c16;
#pragma unroll
        for (int T = 0; T < 8; ++T) {
            const float* wp = W_hh + n * HH + 32 * T + 8 * g;
            const float4 f0 = *(const float4*)wp;
            const float4 f1 = *(const float4*)(wp + 4);
            bi[tc][T][0] = PK(f0.x, f0.y); bi[tc][T][1] = PK(f0.z, f0.w);
            bi[tc][T][2] = PK(f1.x, f1.y); bi[tc][T][3] = PK(f1.z, f1.w);
        }
#pragma unroll
        for (int T = 8; T < 10; ++T) {
            const float* wp = W_ih + n * II + 32 * (T - 8) + 8 * g;
            const float4 f0 = *(const float4*)wp;
            const float4 f1 = *(const float4*)(wp + 4);
            bi[tc][T][0] = PK(f0.x, f0.y); bi[tc][T][1] = PK(f0.z, f0.w);
            bi[tc][T][2] = PK(f1.x, f1.y); bi[tc][T][3] = PK(f1.z, f1.w);
        }
        bv[tc] = b_ih[n] + b_hh[n];
        wf[tc] = W_fc[n];
    }
    // pin: forbid rematerialization/re-fetch inside the loop (R2-R5 lesson)
#pragma unroll
    for (int j = 0; j < 160; ++j) asm volatile("" : "+v"(((int*)bi)[j]));
#pragma unroll
    for (int j = 0; j < 4; ++j) {
        asm volatile("" : "+v"(bv[j]));
        asm volatile("" : "+v"(wf[j]));
    }
    const float bfcw = (w == 0) ? b_fc[0] : 0.0f;  // added once per t

    for (int idx = tid; idx < 2 * HH * 16; idx += NTHR)
        ((__fp16*)hlds)[idx] = (__fp16)0;  // h_0 = 0; b>=1 slots stay 0 forever
    __syncthreads();

    const float* xrow = x + (size_t)b * TT * II;
    float* outb = out + (size_t)b * TT;

    // tr-read lane address: group g region + lane slot; k-tile via offset imm
    const unsigned trbase = (unsigned)(size_t)(&hlds[0][0][0]) + g * 256 + c16 * 8;
    const unsigned trb0 = trbase, trb1 = trbase + 8192;
    // h write pointers (lanes 0-15 only): row 64w+c16, b=0 slot; tc -> +256 halves
    __fp16* hb0 = &hlds[0][64 * w + c16][0];
    __fp16* hb1 = &hlds[1][64 * w + c16][0];

    // x pipeline: xf8/xf9 = frags for step i; slots A/B raw rows i+1, i+2
    v8h xf8, xf9;
    float4 rA0, rA1, rA2, rA3, rB0, rB1, rB2, rB3;
    {
        const float* x0 = xrow;
        xf8 = xfrag(*(const float4*)(x0 + 8 * g), *(const float4*)(x0 + 8 * g + 4));
        xf9 = xfrag(*(const float4*)(x0 + 32 + 8 * g), *(const float4*)(x0 + 36 + 8 * g));
        const float* x1 = xrow + II;
        rA0 = *(const float4*)(x1 + 8 * g);      rA1 = *(const float4*)(x1 + 8 * g + 4);
        rA2 = *(const float4*)(x1 + 32 + 8 * g); rA3 = *(const float4*)(x1 + 36 + 8 * g);
        const float* x2 = xrow + 2 * II;
        rB0 = *(const float4*)(x2 + 8 * g);      rB1 = *(const float4*)(x2 + 8 * g + 4);
        rB2 = *(const float4*)(x2 + 32 + 8 * g); rB3 = *(const float4*)(x2 + 36 + 8 * g);
    }

    float ph = 0.0f;  // deferred head partial of previous step

#define STEP(I, P, R0, R1, R2, R3)                                             \
    {                                                                          \
        const unsigned ta = (P) ? trb1 : trb0;                                 \
        /* tr-reads k-tiles 0-3 (completion in issue order) */                 \
        u64 a00 = trread<0>(ta),    a01 = trread<128>(ta);                     \
        u64 a10 = trread<1024>(ta), a11 = trread<1152>(ta);                    \
        u64 a20 = trread<2048>(ta), a21 = trread<2176>(ta);                    \
        u64 a30 = trread<3072>(ta), a31 = trread<3200>(ta);                    \
        /* deferred head of step I-1: 16-lane DPP reduce + atomic */           \
        if ((I) > 0) {                                                         \
            float hc = ph;                                                     \
            hc = dpp_add<0xB1>(hc);                                            \
            hc = dpp_add<0x4E>(hc);                                            \
            hc = dpp_add<0x141>(hc);                                           \
            hc = dpp_add<0x140>(hc);                                           \
            if (lane == 0) atomicAdd(outb + (I) - 1, hc + bfcw);               \
        }                                                                      \
        /* x-part mfma (k-tiles 8,9), acc init = bias; fills tr latency */     \
        v4f acc0 = MFMA(xf8, BF(0, 8), (v4f){bv[0], bv[0], bv[0], bv[0]}, 0, 0, 0); \
        v4f acc1 = MFMA(xf8, BF(1, 8), (v4f){bv[1], bv[1], bv[1], bv[1]}, 0, 0, 0); \
        v4f acc2 = MFMA(xf8, BF(2, 8), (v4f){bv[2], bv[2], bv[2], bv[2]}, 0, 0, 0); \
        v4f acc3 = MFMA(xf8, BF(3, 8), (v4f){bv[3], bv[3], bv[3], bv[3]}, 0, 0, 0); \
        acc0 = MFMA(xf9, BF(0, 9), acc0, 0, 0, 0);                             \
        acc1 = MFMA(xf9, BF(1, 9), acc1, 0, 0, 0);                             \
        acc2 = MFMA(xf9, BF(2, 9), acc2, 0, 0, 0);                             \
        acc3 = MFMA(xf9, BF(3, 9), acc3, 0, 0, 0);                             \
        /* tr-reads k-tiles 4-7 */                                             \
        u64 a40 = trread<4096>(ta), a41 = trread<4224>(ta);                    \
        u64 a50 = trread<5120>(ta), a51 = trread<5248>(ta);                    \
        u64 a60 = trread<6144>(ta), a61 = trread<6272>(ta);                    \
        u64 a70 = trread<7168>(ta), a71 = trread<7296>(ta);                    \
        /* h-part: per-tile counted waits, mfma chained into acc */            \
        lgkm_wait<14>();                                                       \
        { v8h A = frag2(a00, a01);                                             \
          acc0 = MFMA(A, BF(0, 0), acc0, 0, 0, 0);                             \
          acc1 = MFMA(A, BF(1, 0), acc1, 0, 0, 0);                             \
          acc2 = MFMA(A, BF(2, 0), acc2, 0, 0, 0);                             \
          acc3 = MFMA(A, BF(3, 0), acc3, 0, 0, 0); }                           \
        lgkm_wait<12>();                                                       \
        { v8h A = frag2(a10, a11);                                             \
          acc0 = MFMA(A, BF(0, 1), acc0, 0, 0, 0);                             \
          acc1 = MFMA(A, BF(1, 1), acc1, 0, 0, 0);                             \
          acc2 = MFMA(A, BF(2, 1), acc2, 0, 0, 0);                             \
          acc3 = MFMA(A, BF(3, 1), acc3, 0, 0, 0); }                           \
        lgkm_wait<10>();                                                       \
        { v8h A = frag2(a20, a21);                                             \
          acc0 = MFMA(A, BF(0, 2), acc0, 0, 0, 0);                             \
          acc1 = MFMA(A, BF(1, 2), acc1, 0, 0, 0);                             \
          acc2 = MFMA(A, BF(2, 2), acc2, 0, 0, 0);                             \
          acc3 = MFMA(A, BF(3, 2), acc3, 0, 0, 0); }                           \
        lgkm_wait<8>();                                                        \
        { v8h A = frag2(a30, a31);                                             \
          acc0 = MFMA(A, BF(0, 3), acc0, 0, 0, 0);                             \
          acc1 = MFMA(A, BF(1, 3), acc1, 0, 0, 0);                             \
          acc2 = MFMA(A, BF(2, 3), acc2, 0, 0, 0);                             \
          acc3 = MFMA(A, BF(3, 3), acc3, 0, 0, 0); }                           \
        lgkm_wait<6>();                                                        \
        { v8h A = frag2(a40, a41);                                             \
          acc0 = MFMA(A, BF(0, 4), acc0, 0, 0, 0);                             \
          acc1 = MFMA(A, BF(1, 4), acc1, 0, 0, 0);                             \
          acc2 = MFMA(A, BF(2, 4), acc2, 0, 0, 0);                             \
          acc3 = MFMA(A, BF(3, 4), acc3, 0, 0, 0); }                           \
        lgkm_wait<4>();                                                        \
        { v8h A = frag2(a50, a51);                                             \
          acc0 = MFMA(A, BF(0, 5), acc0, 0, 0, 0);                             \
          acc1 = MFMA(A, BF(1, 5), acc1, 0, 0, 0);                             \
          acc2 = MFMA(A, BF(2, 5), acc2, 0, 0, 0);                             \
          acc3 = MFMA(A, BF(3, 5), acc3, 0, 0, 0); }                           \
        lgkm_wait<2>();                                                        \
        { v8h A = frag2(a60, a61);                                             \
          acc0 = MFMA(A, BF(0, 6), acc0, 0, 0, 0);                             \
          acc1 = MFMA(A, BF(1, 6), acc1, 0, 0, 0);                             \
          acc2 = MFMA(A, BF(2, 6), acc2, 0, 0, 0);                             \
          acc3 = MFMA(A, BF(3, 6), acc3, 0, 0, 0); }                           \
        lgkm_wait<0>();                                                        \
        { v8h A = frag2(a70, a71);                                             \
          acc0 = MFMA(A, BF(0, 7), acc0, 0, 0, 0);                             \
          acc1 = MFMA(A, BF(1, 7), acc1, 0, 0, 0);                             \
          acc2 = MFMA(A, BF(2, 7), acc2, 0, 0, 0);                             \
          acc3 = MFMA(A, BF(3, 7), acc3, 0, 0, 0); }                           \
        /* x pipeline rotate: consume slot (row I+1), refill with row I+3 */   \
        xf8 = xfrag(R0, R1);                                                   \
        xf9 = xfrag(R2, R3);                                                   \
        {                                                                      \
            const int rn = ((I) + 3 < TT) ? ((I) + 3) : (TT - 1);              \
            const float* xp = xrow + rn * II;                                  \
            R0 = *(const float4*)(xp + 8 * g);                                 \
            R1 = *(const float4*)(xp + 8 * g + 4);                             \
            R2 = *(const float4*)(xp + 32 + 8 * g);                            \
            R3 = *(const float4*)(xp + 36 + 8 * g);                            \
        }                                                                      \
        /* tanh on row 0 (the batch), head partial, h write (lanes 0-15) */    \
        const float h0 = ftanh(acc0[0]);                                       \
        const float h1 = ftanh(acc1[0]);                                       \
        const float h2 = ftanh(acc2[0]);                                       \
        const float h3 = ftanh(acc3[0]);                                       \
        ph = fmaf(h3, wf[3], fmaf(h2, wf[2], fmaf(h1, wf[1], h0 * wf[0])));    \
        if (lane < 16) {                                                       \
            __fp16* hp = (P) ? hb0 : hb1;                                      \
            hp[0]   = (__fp16)h0;                                              \
            hp[256] = (__fp16)h1;                                              \
            hp[512] = (__fp16)h2;                                              \
            hp[768] = (__fp16)h3;                                              \
        }                                                                      \
        /* LDS-only barrier: vmcnt NOT drained (x prefetch spans steps) */     \
        asm volatile("s_waitcnt lgkmcnt(0)\n\ts_barrier" ::: "memory");        \
    }

    for (int ib = 0; ib < TT; ib += 2) {
        STEP(ib, 0, rA0, rA1, rA2, rA3)
        STEP(ib + 1, 1, rB0, rB1, rB2, rB3)
    }
#undef STEP

    // final head (step TT-1)
    {
        float hc = ph;
        hc = dpp_add<0xB1>(hc);
        hc = dpp_add<0x4E>(hc);
        hc = dpp_add<0x141>(hc);
        hc = dpp_add<0x140>(hc);
        if (lane == 0) atomicAdd(outb + TT - 1, hc + bfcw);
    }
}

extern "C" void kernel_launch(void* const* d_in, const int* in_sizes, int n_in,
                              void* d_out, int out_size, void* d_ws, size_t ws_size,
                              hipStream_t stream) {
    const float* x    = (const float*)d_in[0];
    const float* W_ih = (const float*)d_in[1];
    const float* W_hh = (const float*)d_in[2];
    const float* b_ih = (const float*)d_in[3];
    const float* b_hh = (const float*)d_in[4];
    const float* W_fc = (const float*)d_in[5];
    const float* b_fc = (const float*)d_in[6];
    float* out = (float*)d_out;

    rnn_fused<<<BB, NTHR, 0, stream>>>(x, W_ih, W_hh, b_ih, b_hh, W_fc, b_fc, out);
}

// Round 7
// 1240.033 us; speedup vs baseline: 1.5556x; 1.1506x over previous
//
#include <hip/hip_runtime.h>

#define BB 64
#define TT 2048
#define II 64
#define HH 256
#define NTHR 256

typedef _Float16 v8h __attribute__((ext_vector_type(8)));
typedef float v4f __attribute__((ext_vector_type(4)));
typedef int v4i __attribute__((ext_vector_type(4)));

#define PK(a, b) __builtin_bit_cast(int, __builtin_amdgcn_cvt_pkrtz((a), (b)))
#define MFMA __builtin_amdgcn_mfma_f32_16x16x32_f16
// B fragment (tc,T) from pinned ints -> v8h (static indices only, rule #20)
#define BF(tc, T) __builtin_bit_cast(v8h, (v4i){bi[tc][T][0], bi[tc][T][1], bi[tc][T][2], bi[tc][T][3]})

// tanh(x) = 1 - 2/(e^{2x}+1); v_exp + v_rcp, correct limits at +-inf.
__device__ __forceinline__ float ftanh(float x) {
    float e = __expf(2.0f * x);
    return 1.0f - 2.0f * __builtin_amdgcn_rcpf(e + 1.0f);
}

// DPP ctrl: 0xB1 quad ^1, 0x4E quad ^2, 0x141 ROW_HALF_MIRROR (eff ^4 after
// ^1,^2), 0x140 ROW_MIRROR (eff ^8). All 16-lane-row scoped -> lane 0 of each
// row ends with the row sum.
template <int CTRL>
__device__ __forceinline__ float dpp_add(float v) {
    int s = __builtin_amdgcn_update_dpp(0, __float_as_int(v), CTRL, 0xF, 0xF, true);
    return v + __int_as_float(s);
}

__device__ __forceinline__ v8h xfrag(const float4 s0, const float4 s1) {
    v4i r = {PK(s0.x, s0.y), PK(s0.z, s0.w), PK(s1.x, s1.y), PK(s1.z, s1.w)};
    return __builtin_bit_cast(v8h, r);
}

// R7: MFMA engine kept (R6: VALU offload verified correct) + LDS bottleneck
// removed. R6 counters: 2.3e7 bank conflicts (tr-reads on a non-8x[32][16]
// layout, m217) + 16 MB of global-atomic WRITE_SIZE were the regression.
// Key fix: batch=1 => A-rows 1-15 are DEAD (MFMA rows don't mix; we only
// read D-row 0, which depends only on A-row 0 = lanes with lane&15==0).
// Other lanes may hold garbage. So h is a flat 256-half row; every lane of
// 16-lane group g reads the GROUP-UNIFORM 16B chunk T*64+g*16 with a plain
// ds_read_b128 (4 distinct chunks + broadcast = conflict-free). 8 reads/step
// replace 16 conflicted tr-reads. Same verified (g,j)->k map as R6.
// Head back to LDS part[] (no global atomics). No manual lgkm pins: plain
// loads, compiler-counted waits (m97 evidence). Acc chains split 10 -> 6+4.
__launch_bounds__(NTHR, 1)
__global__ void rnn_fused(const float* __restrict__ x,
                          const float* __restrict__ W_ih,
                          const float* __restrict__ W_hh,
                          const float* __restrict__ b_ih,
                          const float* __restrict__ b_hh,
                          const float* __restrict__ W_fc,
                          const float* __restrict__ b_fc,
                          float* __restrict__ out) {
    __shared__ __align__(16) __fp16 hlds[2][HH];  // 1 KB, double-buffered
    __shared__ float part[TT + 1][4];             // head partials, 32.8 KB

    const int tid  = threadIdx.x;
    const int b    = blockIdx.x;
    const int lane = tid & 63;
    const int w    = tid >> 6;     // wave 0..3: output cols [64w, 64w+64)
    const int g    = lane >> 4;    // 16-lane group 0..3 (k sub-slice)
    const int c16  = lane & 15;

    // ---- B fragments: bi[tc][T][j]: lane (g,c16) slot j holds
    // W[n = 64w+16tc+c16][k = 32T + 8g + j]  (T=8,9 -> W_ih, k-256)
    int bi[4][10][4];  // 160 VGPRs
    float bv[4], wf[4];
#pragma unroll
    for (int tc = 0; tc < 4; ++tc) {
        const int n = 64 * w + 16 * tc + c16;
#pragma unroll
        for (int T = 0; T < 8; ++T) {
            const float* wp = W_hh + n * HH + 32 * T + 8 * g;
            const float4 f0 = *(const float4*)wp;
            const float4 f1 = *(const float4*)(wp + 4);
            bi[tc][T][0] = PK(f0.x, f0.y); bi[tc][T][1] = PK(f0.z, f0.w);
            bi[tc][T][2] = PK(f1.x, f1.y); bi[tc][T][3] = PK(f1.z, f1.w);
        }
#pragma unroll
        for (int T = 8; T < 10; ++T) {
            const float* wp = W_ih + n * II + 32 * (T - 8) + 8 * g;
            const float4 f0 = *(const float4*)wp;
            const float4 f1 = *(const float4*)(wp + 4);
            bi[tc][T][0] = PK(f0.x, f0.y); bi[tc][T][1] = PK(f0.z, f0.w);
            bi[tc][T][2] = PK(f1.x, f1.y); bi[tc][T][3] = PK(f1.z, f1.w);
        }
        bv[tc] = b_ih[n] + b_hh[n];
        wf[tc] = W_fc[n];
    }
    // pin: forbid rematerialization/re-fetch inside the loop (R2-R5 lesson)
#pragma unroll
    for (int j = 0; j < 160; ++j) asm volatile("" : "+v"(((int*)bi)[j]));
#pragma unroll
    for (int j = 0; j < 4; ++j) {
        asm volatile("" : "+v"(bv[j]));
        asm volatile("" : "+v"(wf[j]));
    }
    const float bfc = b_fc[0];

    for (int idx = tid; idx < 2 * HH; idx += NTHR)
        ((__fp16*)hlds)[idx] = (__fp16)0;  // h_0 = 0
    __syncthreads();

    const float* xrow = x + (size_t)b * TT * II;
    float* outb = out + (size_t)b * TT;

    // h read base: GROUP-UNIFORM chunk address (broadcast within group);
    // k-tile T at byte offset T*64. Only lanes c16==0 feed D-row 0.
    const char* hrd0 = (const char*)&hlds[0][0] + g * 16;
    const char* hrd1 = (const char*)&hlds[1][0] + g * 16;
    // h write (lanes 0-15 only): col = 64w + 16tc + c16, tc -> +16 halves
    __fp16* hwr0 = &hlds[0][64 * w + c16];
    __fp16* hwr1 = &hlds[1][64 * w + c16];

    // x pipeline: xf8/xf9 = frags for step i; slots A/B raw rows i+1, i+2
    v8h xf8, xf9;
    float4 rA0, rA1, rA2, rA3, rB0, rB1, rB2, rB3;
    {
        const float* x0 = xrow;
        xf8 = xfrag(*(const float4*)(x0 + 8 * g), *(const float4*)(x0 + 8 * g + 4));
        xf9 = xfrag(*(const float4*)(x0 + 32 + 8 * g), *(const float4*)(x0 + 36 + 8 * g));
        const float* x1 = xrow + II;
        rA0 = *(const float4*)(x1 + 8 * g);      rA1 = *(const float4*)(x1 + 8 * g + 4);
        rA2 = *(const float4*)(x1 + 32 + 8 * g); rA3 = *(const float4*)(x1 + 36 + 8 * g);
        const float* x2 = xrow + 2 * II;
        rB0 = *(const float4*)(x2 + 8 * g);      rB1 = *(const float4*)(x2 + 8 * g + 4);
        rB2 = *(const float4*)(x2 + 32 + 8 * g); rB3 = *(const float4*)(x2 + 36 + 8 * g);
    }

    float ph = 0.0f;  // per-lane head partial of previous step (pre-reduce)

#define STEP(I, P, R0, R1, R2, R3)                                             \
    {                                                                          \
        /* issue all 8 h-tile reads (conflict-free b128 broadcast) */          \
        const char* hrd = (P) ? hrd1 : hrd0;                                   \
        const v8h hv0 = *(const v8h*)(hrd + 0 * 64);                           \
        const v8h hv1 = *(const v8h*)(hrd + 1 * 64);                           \
        const v8h hv2 = *(const v8h*)(hrd + 2 * 64);                           \
        const v8h hv3 = *(const v8h*)(hrd + 3 * 64);                           \
        const v8h hv4 = *(const v8h*)(hrd + 4 * 64);                           \
        const v8h hv5 = *(const v8h*)(hrd + 5 * 64);                           \
        const v8h hv6 = *(const v8h*)(hrd + 6 * 64);                           \
        const v8h hv7 = *(const v8h*)(hrd + 7 * 64);                           \
        /* deferred head of step I-1: 16-lane DPP reduce, fills read latency */\
        if ((I) > 0) {                                                         \
            float hc = ph;                                                     \
            hc = dpp_add<0xB1>(hc);                                            \
            hc = dpp_add<0x4E>(hc);                                            \
            hc = dpp_add<0x141>(hc);                                           \
            hc = dpp_add<0x140>(hc);                                           \
            if (lane == 0) part[I][w] = hc;                                    \
        }                                                                      \
        /* chain A: bias + x tiles (8,9) + h tiles 0-3  (depth 6) */           \
        v4f aA0 = MFMA(xf8, BF(0, 8), (v4f){bv[0], bv[0], bv[0], bv[0]}, 0, 0, 0); \
        v4f aA1 = MFMA(xf8, BF(1, 8), (v4f){bv[1], bv[1], bv[1], bv[1]}, 0, 0, 0); \
        v4f aA2 = MFMA(xf8, BF(2, 8), (v4f){bv[2], bv[2], bv[2], bv[2]}, 0, 0, 0); \
        v4f aA3 = MFMA(xf8, BF(3, 8), (v4f){bv[3], bv[3], bv[3], bv[3]}, 0, 0, 0); \
        aA0 = MFMA(xf9, BF(0, 9), aA0, 0, 0, 0);                               \
        aA1 = MFMA(xf9, BF(1, 9), aA1, 0, 0, 0);                               \
        aA2 = MFMA(xf9, BF(2, 9), aA2, 0, 0, 0);                               \
        aA3 = MFMA(xf9, BF(3, 9), aA3, 0, 0, 0);                               \
        aA0 = MFMA(hv0, BF(0, 0), aA0, 0, 0, 0);                               \
        aA1 = MFMA(hv0, BF(1, 0), aA1, 0, 0, 0);                               \
        aA2 = MFMA(hv0, BF(2, 0), aA2, 0, 0, 0);                               \
        aA3 = MFMA(hv0, BF(3, 0), aA3, 0, 0, 0);                               \
        aA0 = MFMA(hv1, BF(0, 1), aA0, 0, 0, 0);                               \
        aA1 = MFMA(hv1, BF(1, 1), aA1, 0, 0, 0);                               \
        aA2 = MFMA(hv1, BF(2, 1), aA2, 0, 0, 0);                               \
        aA3 = MFMA(hv1, BF(3, 1), aA3, 0, 0, 0);                               \
        aA0 = MFMA(hv2, BF(0, 2), aA0, 0, 0, 0);                               \
        aA1 = MFMA(hv2, BF(1, 2), aA1, 0, 0, 0);                               \
        aA2 = MFMA(hv2, BF(2, 2), aA2, 0, 0, 0);                               \
        aA3 = MFMA(hv2, BF(3, 2), aA3, 0, 0, 0);                               \
        aA0 = MFMA(hv3, BF(0, 3), aA0, 0, 0, 0);                               \
        aA1 = MFMA(hv3, BF(1, 3), aA1, 0, 0, 0);                               \
        aA2 = MFMA(hv3, BF(2, 3), aA2, 0, 0, 0);                               \
        aA3 = MFMA(hv3, BF(3, 3), aA3, 0, 0, 0);                               \
        /* chain B: h tiles 4-7 from zero  (depth 4, independent) */           \
        v4f aB0 = MFMA(hv4, BF(0, 4), (v4f){0.f, 0.f, 0.f, 0.f}, 0, 0, 0);     \
        v4f aB1 = MFMA(hv4, BF(1, 4), (v4f){0.f, 0.f, 0.f, 0.f}, 0, 0, 0);     \
        v4f aB2 = MFMA(hv4, BF(2, 4), (v4f){0.f, 0.f, 0.f, 0.f}, 0, 0, 0);     \
        v4f aB3 = MFMA(hv4, BF(3, 4), (v4f){0.f, 0.f, 0.f, 0.f}, 0, 0, 0);     \
        aB0 = MFMA(hv5, BF(0, 5), aB0, 0, 0, 0);                               \
        aB1 = MFMA(hv5, BF(1, 5), aB1, 0, 0, 0);                               \
        aB2 = MFMA(hv5, BF(2, 5), aB2, 0, 0, 0);                               \
        aB3 = MFMA(hv5, BF(3, 5), aB3, 0, 0, 0);                               \
        aB0 = MFMA(hv6, BF(0, 6), aB0, 0, 0, 0);                               \
        aB1 = MFMA(hv6, BF(1, 6), aB1, 0, 0, 0);                               \
        aB2 = MFMA(hv6, BF(2, 6), aB2, 0, 0, 0);                               \
        aB3 = MFMA(hv6, BF(3, 6), aB3, 0, 0, 0);                               \
        aB0 = MFMA(hv7, BF(0, 7), aB0, 0, 0, 0);                               \
        aB1 = MFMA(hv7, BF(1, 7), aB1, 0, 0, 0);                               \
        aB2 = MFMA(hv7, BF(2, 7), aB2, 0, 0, 0);                               \
        aB3 = MFMA(hv7, BF(3, 7), aB3, 0, 0, 0);                               \
        /* x pipeline rotate: consume slot (row I+1), refill with row I+3 */   \
        xf8 = xfrag(R0, R1);                                                   \
        xf9 = xfrag(R2, R3);                                                   \
        {                                                                      \
            const int rn = ((I) + 3 < TT) ? ((I) + 3) : (TT - 1);              \
            const float* xp = xrow + rn * II;                                  \
            R0 = *(const float4*)(xp + 8 * g);                                 \
            R1 = *(const float4*)(xp + 8 * g + 4);                             \
            R2 = *(const float4*)(xp + 32 + 8 * g);                            \
            R3 = *(const float4*)(xp + 36 + 8 * g);                            \
        }                                                                      \
        /* tanh on D-row 0 (valid on lanes g==0; bounded garbage elsewhere) */ \
        const float h0 = ftanh(aA0[0] + aB0[0]);                               \
        const float h1 = ftanh(aA1[0] + aB1[0]);                               \
        const float h2 = ftanh(aA2[0] + aB2[0]);                               \
        const float h3 = ftanh(aA3[0] + aB3[0]);                               \
        ph = fmaf(h3, wf[3], fmaf(h2, wf[2], fmaf(h1, wf[1], h0 * wf[0])));    \
        if (lane < 16) {                                                       \
            __fp16* hp = (P) ? hwr0 : hwr1;                                    \
            hp[0]  = (__fp16)h0;                                               \
            hp[16] = (__fp16)h1;                                               \
            hp[32] = (__fp16)h2;                                               \
            hp[48] = (__fp16)h3;                                               \
        }                                                                      \
        /* LDS-only barrier: vmcnt NOT drained (x prefetch spans steps) */     \
        asm volatile("s_waitcnt lgkmcnt(0)\n\ts_barrier" ::: "memory");        \
    }

    for (int ib = 0; ib < TT; ib += 2) {
        STEP(ib, 0, rA0, rA1, rA2, rA3)
        STEP(ib + 1, 1, rB0, rB1, rB2, rB3)
    }
#undef STEP

    // final head (step TT-1) -> part[TT]
    {
        float hc = ph;
        hc = dpp_add<0xB1>(hc);
        hc = dpp_add<0x4E>(hc);
        hc = dpp_add<0x141>(hc);
        hc = dpp_add<0x140>(hc);
        if (lane == 0) part[TT][w] = hc;
    }
    __syncthreads();

    // ---- deferred output head: out[b][i] = sum(part[i+1][0..3]) + bfc ----
    for (int i = tid; i < TT; i += NTHR) {
        const float4 s = *(const float4*)&part[i + 1][0];
        outb[i] = s.x + s.y + s.z + s.w + bfc;
    }
}

extern "C" void kernel_launch(void* const* d_in, const int* in_sizes, int n_in,
                              void* d_out, int out_size, void* d_ws, size_t ws_size,
                              hipStream_t stream) {
    const float* x    = (const float*)d_in[0];
    const float* W_ih = (const float*)d_in[1];
    const float* W_hh = (const float*)d_in[2];
    const float* b_ih = (const float*)d_in[3];
    const float* b_hh = (const float*)d_in[4];
    const float* W_fc = (const float*)d_in[5];
    const float* b_fc = (const float*)d_in[6];
    float* out = (float*)d_out;

    rnn_fused<<<BB, NTHR, 0, stream>>>(x, W_ih, W_hh, b_ih, b_hh, W_fc, b_fc, out);
}